// Round 1
// baseline (50319.586 us; speedup 1.0000x reference)
//
#include <hip/hip_runtime.h>
#include <hip/hip_fp16.h>

#define T_LEN 2048
#define HID   2048
#define G4    8192
#define NV    128

// ---------------- GEMM: C[M][N] = A[M][K] @ B[N][K]^T + (b1+b2)[N] ----------------
// M=2048, N=8192, K=2048. 64x64 tile, K-tile 32, 256 threads, 4x4 outputs/thread.
__global__ __launch_bounds__(256, 2) void gemm_bias(
    const float* __restrict__ A, const float* __restrict__ B,
    const float* __restrict__ b1, const float* __restrict__ b2,
    float* __restrict__ C)
{
  const int N = 8192, K = 2048;
  __shared__ float As[32][68];   // k-major, pad to 68 floats (16B-aligned rows)
  __shared__ float Bs[32][68];
  const int tid = threadIdx.x;
  const int tx = tid & 15, ty = tid >> 4;
  const int row0 = blockIdx.y * 64, col0 = blockIdx.x * 64;
  const int lk = (tid & 7) * 4, lr = tid >> 3;   // loader: k-quad, row 0..31
  float acc[4][4] = {};
  for (int k0 = 0; k0 < K; k0 += 32) {
    float4 a0  = *(const float4*)&A[(size_t)(row0 + lr)      * K + k0 + lk];
    float4 a1  = *(const float4*)&A[(size_t)(row0 + lr + 32) * K + k0 + lk];
    float4 bb0 = *(const float4*)&B[(size_t)(col0 + lr)      * K + k0 + lk];
    float4 bb1 = *(const float4*)&B[(size_t)(col0 + lr + 32) * K + k0 + lk];
    __syncthreads();
    As[lk+0][lr] = a0.x;  As[lk+1][lr] = a0.y;  As[lk+2][lr] = a0.z;  As[lk+3][lr] = a0.w;
    As[lk+0][lr+32] = a1.x; As[lk+1][lr+32] = a1.y; As[lk+2][lr+32] = a1.z; As[lk+3][lr+32] = a1.w;
    Bs[lk+0][lr] = bb0.x; Bs[lk+1][lr] = bb0.y; Bs[lk+2][lr] = bb0.z; Bs[lk+3][lr] = bb0.w;
    Bs[lk+0][lr+32] = bb1.x; Bs[lk+1][lr+32] = bb1.y; Bs[lk+2][lr+32] = bb1.z; Bs[lk+3][lr+32] = bb1.w;
    __syncthreads();
    #pragma unroll
    for (int kk = 0; kk < 32; ++kk) {
      float4 av = *(const float4*)&As[kk][ty * 4];
      float4 bv = *(const float4*)&Bs[kk][tx * 4];
      float am[4] = {av.x, av.y, av.z, av.w};
      float bm[4] = {bv.x, bv.y, bv.z, bv.w};
      #pragma unroll
      for (int i = 0; i < 4; ++i)
        #pragma unroll
        for (int j = 0; j < 4; ++j)
          acc[i][j] = fmaf(am[i], bm[j], acc[i][j]);
    }
  }
  #pragma unroll
  for (int i = 0; i < 4; ++i) {
    const int r = row0 + ty * 4 + i;
    #pragma unroll
    for (int j = 0; j < 4; ++j) {
      const int cc = col0 + tx * 4 + j;
      C[(size_t)r * N + cc] = acc[i][j] + b1[cc] + b2[cc];
    }
  }
}

// ---------------- Persistent recurrent kernel (one layer) ----------------
// 256 WGs x 512 threads. WG b owns h indices [8b, 8b+8); wave w computes all 4
// gates of h index j = 8b+w. W_hh slice lives in VGPRs as packed f16.
// Per-step device-scope sync: write h -> release flag; poll 256 flags -> acquire.
__global__ __launch_bounds__(512, 2) void lstm_rec(
    const float* __restrict__ Whh,   // [8192][2048] this layer
    const float* __restrict__ G,     // [T][8192]  precomputed x-contribution + biases
    const float* __restrict__ h0,    // [2048]
    const float* __restrict__ c0,    // [2048]
    float* __restrict__ Hbuf,        // [T+1][2048]; row 0 = h0, row r = h_t (t=r-1)
    int* flags,                      // [256], zero-initialized
    float* __restrict__ hn, float* __restrict__ cn)
{
  const int b = blockIdx.x;
  const int tid = threadIdx.x;
  const int w = tid >> 6;
  const int lane = tid & 63;
  const int j = b * 8 + w;
  __shared__ float h_lds[HID];

  // Load per-lane weight fragment: lane holds elements {2*lane, 2*lane+1} + 128*it
  // of rows gate*2048+j, packed f32->f16 (64 VGPRs).
  __half2 wreg[4][16];
  #pragma unroll
  for (int g = 0; g < 4; ++g) {
    const float* wrow = Whh + (size_t)(g * 2048 + j) * 2048 + 2 * lane;
    #pragma unroll
    for (int it = 0; it < 16; ++it) {
      float2 wv = *(const float2*)(wrow + 128 * it);
      wreg[g][it] = __floats2half2_rn(wv.x, wv.y);
    }
  }

  float cval = 0.f, hlast = 0.f;
  if (lane == 0) cval = c0[j];

  // Publish row 0 (= h0)
  {
    float4 hv = *(const float4*)&h0[tid * 4];
    *(float4*)&Hbuf[tid * 4] = hv;
  }
  __syncthreads();
  if (tid == 0) __hip_atomic_store(&flags[b], 1, __ATOMIC_RELEASE, __HIP_MEMORY_SCOPE_AGENT);

  for (int r = 1; r <= T_LEN; ++r) {
    // Prefetch this step's G values early (independent of the flag wait).
    float gpre = (lane < 4) ? G[(size_t)(r - 1) * G4 + lane * 2048 + j] : 0.f;

    if (w == 0) {  // wave 0 polls all 256 flags (4 per lane)
      int spins = 0;
      for (;;) {
        int f0 = __hip_atomic_load(&flags[lane],       __ATOMIC_RELAXED, __HIP_MEMORY_SCOPE_AGENT);
        int f1 = __hip_atomic_load(&flags[lane + 64],  __ATOMIC_RELAXED, __HIP_MEMORY_SCOPE_AGENT);
        int f2 = __hip_atomic_load(&flags[lane + 128], __ATOMIC_RELAXED, __HIP_MEMORY_SCOPE_AGENT);
        int f3 = __hip_atomic_load(&flags[lane + 192], __ATOMIC_RELAXED, __HIP_MEMORY_SCOPE_AGENT);
        bool ok = (f0 >= r) & (f1 >= r) & (f2 >= r) & (f3 >= r);
        if (__all((int)ok)) break;
        if (++spins > (1 << 26)) break;  // safety valve against deadlock
      }
      __builtin_amdgcn_fence(__ATOMIC_ACQUIRE, "agent");  // invalidate L1/L2 before h reads
    }
    __syncthreads();

    // Stage h_{r-1} into LDS (fresh from coherence point after acquire).
    {
      float4 hv = *(const float4*)&Hbuf[(size_t)(r - 1) * HID + tid * 4];
      *(float4*)&h_lds[tid * 4] = hv;
    }
    __syncthreads();

    float a0 = 0.f, a1 = 0.f, a2 = 0.f, a3 = 0.f;
    #pragma unroll
    for (int it = 0; it < 16; ++it) {
      float2 hv = *(const float2*)&h_lds[2 * lane + 128 * it];
      float2 w0 = __half22float2(wreg[0][it]);
      float2 w1 = __half22float2(wreg[1][it]);
      float2 w2 = __half22float2(wreg[2][it]);
      float2 w3 = __half22float2(wreg[3][it]);
      a0 = fmaf(w0.x, hv.x, a0); a0 = fmaf(w0.y, hv.y, a0);
      a1 = fmaf(w1.x, hv.x, a1); a1 = fmaf(w1.y, hv.y, a1);
      a2 = fmaf(w2.x, hv.x, a2); a2 = fmaf(w2.y, hv.y, a2);
      a3 = fmaf(w3.x, hv.x, a3); a3 = fmaf(w3.y, hv.y, a3);
    }
    #pragma unroll
    for (int off = 32; off > 0; off >>= 1) {
      a0 += __shfl_xor(a0, off, 64);
      a1 += __shfl_xor(a1, off, 64);
      a2 += __shfl_xor(a2, off, 64);
      a3 += __shfl_xor(a3, off, 64);
    }
    float g0 = __shfl(gpre, 0, 64), g1 = __shfl(gpre, 1, 64);
    float g2 = __shfl(gpre, 2, 64), g3 = __shfl(gpre, 3, 64);
    if (lane == 0) {
      float pi = a0 + g0, pf = a1 + g1, pg = a2 + g2, po = a3 + g3;
      float ig = 1.f / (1.f + expf(-pi));
      float fg = 1.f / (1.f + expf(-pf));
      float gg = tanhf(pg);
      float og = 1.f / (1.f + expf(-po));
      cval = fg * cval + ig * gg;
      hlast = og * tanhf(cval);
      Hbuf[(size_t)r * HID + j] = hlast;
    }
    __syncthreads();   // drains each wave's store (vmcnt(0) before s_barrier)
    // release: fence (wbl2) + flag store; all WG stores are already in L2
    if (tid == 0) __hip_atomic_store(&flags[b], r + 1, __ATOMIC_RELEASE, __HIP_MEMORY_SCOPE_AGENT);
  }
  if (lane == 0) { hn[j] = hlast; cn[j] = cval; }
}

// ---------------- FC + log_softmax ----------------
// grid = T blocks x 128 threads; thread v computes logits[t][v] then block softmax.
__global__ __launch_bounds__(128) void fc_lsm(
    const float* __restrict__ Hrows,  // [T][2048] (Hbuf1 + HID)
    const float* __restrict__ fcw,    // [128][2048]
    const float* __restrict__ fcb,    // [128]
    float* __restrict__ out)          // [T][128]
{
  const int t = blockIdx.x;
  const int v = threadIdx.x;
  __shared__ float hs[HID];
  __shared__ float red[4];
  const float* hrow = Hrows + (size_t)t * HID;
  for (int q = v; q < HID / 4; q += 128)
    *(float4*)&hs[q * 4] = *(const float4*)&hrow[q * 4];
  __syncthreads();
  const float* wrow = fcw + (size_t)v * HID;
  float acc = fcb[v];
  #pragma unroll 4
  for (int k = 0; k < HID; k += 4) {
    float4 wv = *(const float4*)&wrow[k];
    acc = fmaf(wv.x, hs[k],     acc);
    acc = fmaf(wv.y, hs[k + 1], acc);
    acc = fmaf(wv.z, hs[k + 2], acc);
    acc = fmaf(wv.w, hs[k + 3], acc);
  }
  float m = acc;
  #pragma unroll
  for (int off = 32; off > 0; off >>= 1) m = fmaxf(m, __shfl_xor(m, off, 64));
  if ((v & 63) == 0) red[v >> 6] = m;
  __syncthreads();
  m = fmaxf(red[0], red[1]);
  float e = expf(acc - m), s = e;
  #pragma unroll
  for (int off = 32; off > 0; off >>= 1) s += __shfl_xor(s, off, 64);
  if ((v & 63) == 0) red[2 + (v >> 6)] = s;
  __syncthreads();
  s = red[2] + red[3];
  out[(size_t)t * NV + v] = (acc - m) - logf(s);
}

extern "C" void kernel_launch(void* const* d_in, const int* in_sizes, int n_in,
                              void* d_out, int out_size, void* d_ws, size_t ws_size,
                              hipStream_t stream) {
  const float* x   = (const float*)d_in[0];
  const float* h0  = (const float*)d_in[1];
  const float* c0  = (const float*)d_in[2];
  const float* Wih = (const float*)d_in[3];
  const float* Whh = (const float*)d_in[4];
  const float* bih = (const float*)d_in[5];
  const float* bhh = (const float*)d_in[6];
  const float* fcw = (const float*)d_in[7];
  const float* fcb = (const float*)d_in[8];
  float* out = (float*)d_out;

  // ws layout (bytes): G 67,108,864 | Hbuf0 16,785,408 | Hbuf1 16,785,408 | flags 2KB
  char* ws = (char*)d_ws;
  float* G      = (float*)(ws);
  float* Hbuf0  = (float*)(ws + 67108864);
  float* Hbuf1  = (float*)(ws + 67108864 + 16785408);
  int*   flags0 = (int*)  (ws + 67108864 + 2 * 16785408);
  int*   flags1 = flags0 + 256;

  hipMemsetAsync(flags0, 0, 2 * 256 * sizeof(int), stream);

  dim3 ggrid(G4 / 64, T_LEN / 64);  // (128, 32)

  // layer 0
  gemm_bias<<<ggrid, 256, 0, stream>>>(x, Wih, bih, bhh, G);
  lstm_rec<<<256, 512, 0, stream>>>(Whh, G, h0, c0, Hbuf0, flags0,
                                    out + 262144, out + 266240);
  // layer 1 (input = layer-0 outputs, Hbuf0 rows 1..T)
  gemm_bias<<<ggrid, 256, 0, stream>>>(Hbuf0 + HID, Wih + (size_t)G4 * HID,
                                       bih + G4, bhh + G4, G);
  lstm_rec<<<256, 512, 0, stream>>>(Whh + (size_t)G4 * HID, G, h0 + HID, c0 + HID,
                                    Hbuf1, flags1,
                                    out + 262144 + HID, out + 266240 + HID);
  // FC + log_softmax on layer-1 outputs
  fc_lsm<<<T_LEN, 128, 0, stream>>>(Hbuf1 + HID, fcw, fcb, out);
}

// Round 2
// 32755.588 us; speedup vs baseline: 1.5362x; 1.5362x over previous
//
#include <hip/hip_runtime.h>
#include <hip/hip_fp16.h>

#define T_LEN 2048
#define HID   2048
#define G4    8192
#define NV    128

// ---------------- GEMM: C[M][N] = A[M][K] @ B[N][K]^T + (b1+b2)[N] ----------------
// M=2048, N=8192, K=2048. 64x64 tile, K-tile 32, 256 threads, 4x4 outputs/thread.
__global__ __launch_bounds__(256, 2) void gemm_bias(
    const float* __restrict__ A, const float* __restrict__ B,
    const float* __restrict__ b1, const float* __restrict__ b2,
    float* __restrict__ C)
{
  const int N = 8192, K = 2048;
  __shared__ float As[32][68];   // k-major, pad to 68 floats (16B-aligned rows)
  __shared__ float Bs[32][68];
  const int tid = threadIdx.x;
  const int tx = tid & 15, ty = tid >> 4;
  const int row0 = blockIdx.y * 64, col0 = blockIdx.x * 64;
  const int lk = (tid & 7) * 4, lr = tid >> 3;   // loader: k-quad, row 0..31
  float acc[4][4] = {};
  for (int k0 = 0; k0 < K; k0 += 32) {
    float4 a0  = *(const float4*)&A[(size_t)(row0 + lr)      * K + k0 + lk];
    float4 a1  = *(const float4*)&A[(size_t)(row0 + lr + 32) * K + k0 + lk];
    float4 bb0 = *(const float4*)&B[(size_t)(col0 + lr)      * K + k0 + lk];
    float4 bb1 = *(const float4*)&B[(size_t)(col0 + lr + 32) * K + k0 + lk];
    __syncthreads();
    As[lk+0][lr] = a0.x;  As[lk+1][lr] = a0.y;  As[lk+2][lr] = a0.z;  As[lk+3][lr] = a0.w;
    As[lk+0][lr+32] = a1.x; As[lk+1][lr+32] = a1.y; As[lk+2][lr+32] = a1.z; As[lk+3][lr+32] = a1.w;
    Bs[lk+0][lr] = bb0.x; Bs[lk+1][lr] = bb0.y; Bs[lk+2][lr] = bb0.z; Bs[lk+3][lr] = bb0.w;
    Bs[lk+0][lr+32] = bb1.x; Bs[lk+1][lr+32] = bb1.y; Bs[lk+2][lr+32] = bb1.z; Bs[lk+3][lr+32] = bb1.w;
    __syncthreads();
    #pragma unroll
    for (int kk = 0; kk < 32; ++kk) {
      float4 av = *(const float4*)&As[kk][ty * 4];
      float4 bv = *(const float4*)&Bs[kk][tx * 4];
      float am[4] = {av.x, av.y, av.z, av.w};
      float bm[4] = {bv.x, bv.y, bv.z, bv.w};
      #pragma unroll
      for (int i = 0; i < 4; ++i)
        #pragma unroll
        for (int j = 0; j < 4; ++j)
          acc[i][j] = fmaf(am[i], bm[j], acc[i][j]);
    }
  }
  #pragma unroll
  for (int i = 0; i < 4; ++i) {
    const int r = row0 + ty * 4 + i;
    #pragma unroll
    for (int j = 0; j < 4; ++j) {
      const int cc = col0 + tx * 4 + j;
      C[(size_t)r * N + cc] = acc[i][j] + b1[cc] + b2[cc];
    }
  }
}

// ---------------- Persistent recurrent kernel (one layer) ----------------
// 256 WGs x 512 threads. WG b owns h indices [8b, 8b+8); wave w computes all 4
// gates of h index j = 8b+w. W_hh slice lives in VGPRs as packed f16.
//
// Cross-WG handoff uses ONLY relaxed agent-scope atomics (per-instruction sc
// bits bypass the non-coherent per-XCD L1/L2 and hit the coherent point).
// NO acquire/release fences in the loop: on gfx950 those lower to full-L2
// buffer_inv / buffer_wbl2 (~27K cycles = the 11 us/step seen in R1).
// Ordering: producer drains stores with s_waitcnt vmcnt(0) (+barrier) before
// the flag store; consumer's h loads are control-dependent on the flag spin
// plus a compiler memory barrier.
__global__ __launch_bounds__(512, 2) void lstm_rec(
    const float* __restrict__ Whh,   // [8192][2048] this layer
    const float* __restrict__ G,     // [T][8192]  precomputed x-contribution + biases
    const float* __restrict__ h0,    // [2048]
    const float* __restrict__ c0,    // [2048]
    float* Hbuf,                     // [T+1][2048]; row 0 = h0, row r = h_t (t=r-1)
    int* flags,                      // [256], zero-initialized
    float* __restrict__ hn, float* __restrict__ cn)
{
  const int b = blockIdx.x;
  const int tid = threadIdx.x;
  const int w = tid >> 6;
  const int lane = tid & 63;
  const int j = b * 8 + w;
  __shared__ float h_lds[HID];

  // Load per-lane weight fragment: lane holds elements {2*lane, 2*lane+1} + 128*it
  // of rows gate*2048+j, packed f32->f16 (64 VGPRs).
  __half2 wreg[4][16];
  #pragma unroll
  for (int g = 0; g < 4; ++g) {
    const float* wrow = Whh + (size_t)(g * 2048 + j) * 2048 + 2 * lane;
    #pragma unroll
    for (int it = 0; it < 16; ++it) {
      float2 wv = *(const float2*)(wrow + 128 * it);
      wreg[g][it] = __floats2half2_rn(wv.x, wv.y);
    }
  }

  float cval = 0.f, hlast = 0.f;
  if (lane == 0) cval = c0[j];

  // Publish this WG's 8 elements of row 0 (= h0) via coherent stores.
  if (tid < 8)
    __hip_atomic_store(&Hbuf[b * 8 + tid], h0[b * 8 + tid],
                       __ATOMIC_RELAXED, __HIP_MEMORY_SCOPE_AGENT);
  __builtin_amdgcn_s_waitcnt(0);
  __syncthreads();
  if (tid == 0)
    __hip_atomic_store(&flags[b], 1, __ATOMIC_RELAXED, __HIP_MEMORY_SCOPE_AGENT);

  for (int r = 1; r <= T_LEN; ++r) {
    // Prefetch this step's G values early (independent of the flag wait).
    float gpre = (lane < 4) ? G[(size_t)(r - 1) * G4 + lane * 2048 + j] : 0.f;

    if (w == 0) {  // wave 0 polls all 256 flags (4 per lane)
      int spins = 0;
      for (;;) {
        int f0 = __hip_atomic_load(&flags[lane],       __ATOMIC_RELAXED, __HIP_MEMORY_SCOPE_AGENT);
        int f1 = __hip_atomic_load(&flags[lane + 64],  __ATOMIC_RELAXED, __HIP_MEMORY_SCOPE_AGENT);
        int f2 = __hip_atomic_load(&flags[lane + 128], __ATOMIC_RELAXED, __HIP_MEMORY_SCOPE_AGENT);
        int f3 = __hip_atomic_load(&flags[lane + 192], __ATOMIC_RELAXED, __HIP_MEMORY_SCOPE_AGENT);
        bool ok = (f0 >= r) & (f1 >= r) & (f2 >= r) & (f3 >= r);
        if (__all((int)ok)) break;
        if (++spins > (1 << 27)) break;  // safety valve against deadlock
      }
      __asm__ volatile("" ::: "memory");  // compiler-only: keep h loads below the spin
    }
    __syncthreads();

    // Stage h_{r-1} into LDS with coherent (L1/L2-bypassing) loads.
    {
      const float* Hrow = Hbuf + (size_t)(r - 1) * HID;
      #pragma unroll
      for (int q = 0; q < 4; ++q) {
        const int idx = tid + q * 512;
        h_lds[idx] = __hip_atomic_load(&Hrow[idx],
                                       __ATOMIC_RELAXED, __HIP_MEMORY_SCOPE_AGENT);
      }
    }
    __syncthreads();

    float a0 = 0.f, a1 = 0.f, a2 = 0.f, a3 = 0.f;
    #pragma unroll
    for (int it = 0; it < 16; ++it) {
      float2 hv = *(const float2*)&h_lds[2 * lane + 128 * it];
      float2 w0 = __half22float2(wreg[0][it]);
      float2 w1 = __half22float2(wreg[1][it]);
      float2 w2 = __half22float2(wreg[2][it]);
      float2 w3 = __half22float2(wreg[3][it]);
      a0 = fmaf(w0.x, hv.x, a0); a0 = fmaf(w0.y, hv.y, a0);
      a1 = fmaf(w1.x, hv.x, a1); a1 = fmaf(w1.y, hv.y, a1);
      a2 = fmaf(w2.x, hv.x, a2); a2 = fmaf(w2.y, hv.y, a2);
      a3 = fmaf(w3.x, hv.x, a3); a3 = fmaf(w3.y, hv.y, a3);
    }
    #pragma unroll
    for (int off = 32; off > 0; off >>= 1) {
      a0 += __shfl_xor(a0, off, 64);
      a1 += __shfl_xor(a1, off, 64);
      a2 += __shfl_xor(a2, off, 64);
      a3 += __shfl_xor(a3, off, 64);
    }
    float g0 = __shfl(gpre, 0, 64), g1 = __shfl(gpre, 1, 64);
    float g2 = __shfl(gpre, 2, 64), g3 = __shfl(gpre, 3, 64);
    if (lane == 0) {
      float pi = a0 + g0, pf = a1 + g1, pg = a2 + g2, po = a3 + g3;
      float ig = 1.f / (1.f + expf(-pi));
      float fg = 1.f / (1.f + expf(-pf));
      float gg = tanhf(pg);
      float og = 1.f / (1.f + expf(-po));
      cval = fg * cval + ig * gg;
      hlast = og * tanhf(cval);
      __hip_atomic_store(&Hbuf[(size_t)r * HID + j], hlast,
                         __ATOMIC_RELAXED, __HIP_MEMORY_SCOPE_AGENT);
    }
    // Drain every wave's h store to the coherence point, then barrier, then flag.
    __builtin_amdgcn_s_waitcnt(0);
    __syncthreads();
    if (tid == 0)
      __hip_atomic_store(&flags[b], r + 1, __ATOMIC_RELAXED, __HIP_MEMORY_SCOPE_AGENT);
  }
  if (lane == 0) { hn[j] = hlast; cn[j] = cval; }
}

// ---------------- FC + log_softmax ----------------
// grid = T blocks x 128 threads; thread v computes logits[t][v] then block softmax.
__global__ __launch_bounds__(128) void fc_lsm(
    const float* __restrict__ Hrows,  // [T][2048] (Hbuf1 + HID)
    const float* __restrict__ fcw,    // [128][2048]
    const float* __restrict__ fcb,    // [128]
    float* __restrict__ out)          // [T][128]
{
  const int t = blockIdx.x;
  const int v = threadIdx.x;
  __shared__ float hs[HID];
  __shared__ float red[4];
  const float* hrow = Hrows + (size_t)t * HID;
  for (int q = v; q < HID / 4; q += 128)
    *(float4*)&hs[q * 4] = *(const float4*)&hrow[q * 4];
  __syncthreads();
  const float* wrow = fcw + (size_t)v * HID;
  float acc = fcb[v];
  #pragma unroll 4
  for (int k = 0; k < HID; k += 4) {
    float4 wv = *(const float4*)&wrow[k];
    acc = fmaf(wv.x, hs[k],     acc);
    acc = fmaf(wv.y, hs[k + 1], acc);
    acc = fmaf(wv.z, hs[k + 2], acc);
    acc = fmaf(wv.w, hs[k + 3], acc);
  }
  float m = acc;
  #pragma unroll
  for (int off = 32; off > 0; off >>= 1) m = fmaxf(m, __shfl_xor(m, off, 64));
  if ((v & 63) == 0) red[v >> 6] = m;
  __syncthreads();
  m = fmaxf(red[0], red[1]);
  float e = expf(acc - m), s = e;
  #pragma unroll
  for (int off = 32; off > 0; off >>= 1) s += __shfl_xor(s, off, 64);
  if ((v & 63) == 0) red[2 + (v >> 6)] = s;
  __syncthreads();
  s = red[2] + red[3];
  out[(size_t)t * NV + v] = (acc - m) - logf(s);
}

extern "C" void kernel_launch(void* const* d_in, const int* in_sizes, int n_in,
                              void* d_out, int out_size, void* d_ws, size_t ws_size,
                              hipStream_t stream) {
  const float* x   = (const float*)d_in[0];
  const float* h0  = (const float*)d_in[1];
  const float* c0  = (const float*)d_in[2];
  const float* Wih = (const float*)d_in[3];
  const float* Whh = (const float*)d_in[4];
  const float* bih = (const float*)d_in[5];
  const float* bhh = (const float*)d_in[6];
  const float* fcw = (const float*)d_in[7];
  const float* fcb = (const float*)d_in[8];
  float* out = (float*)d_out;

  // ws layout (bytes): G 67,108,864 | Hbuf0 16,785,408 | Hbuf1 16,785,408 | flags 2KB
  char* ws = (char*)d_ws;
  float* G      = (float*)(ws);
  float* Hbuf0  = (float*)(ws + 67108864);
  float* Hbuf1  = (float*)(ws + 67108864 + 16785408);
  int*   flags0 = (int*)  (ws + 67108864 + 2 * 16785408);
  int*   flags1 = flags0 + 256;

  hipMemsetAsync(flags0, 0, 2 * 256 * sizeof(int), stream);

  dim3 ggrid(G4 / 64, T_LEN / 64);  // (128, 32)

  // layer 0
  gemm_bias<<<ggrid, 256, 0, stream>>>(x, Wih, bih, bhh, G);
  lstm_rec<<<256, 512, 0, stream>>>(Whh, G, h0, c0, Hbuf0, flags0,
                                    out + 262144, out + 266240);
  // layer 1 (input = layer-0 outputs, Hbuf0 rows 1..T)
  gemm_bias<<<ggrid, 256, 0, stream>>>(Hbuf0 + HID, Wih + (size_t)G4 * HID,
                                       bih + G4, bhh + G4, G);
  lstm_rec<<<256, 512, 0, stream>>>(Whh + (size_t)G4 * HID, G, h0 + HID, c0 + HID,
                                    Hbuf1, flags1,
                                    out + 262144 + HID, out + 266240 + HID);
  // FC + log_softmax on layer-1 outputs
  fc_lsm<<<T_LEN, 128, 0, stream>>>(Hbuf1 + HID, fcw, fcb, out);
}

// Round 3
// 24309.213 us; speedup vs baseline: 2.0700x; 1.3475x over previous
//
#include <hip/hip_runtime.h>
#include <hip/hip_fp16.h>

#define T_LEN 2048
#define HID   2048
#define G4    8192
#define NV    128

__device__ __forceinline__ float uph(unsigned u) {
  return __half2float(__ushort_as_half((unsigned short)(u & 0xffffu)));
}
__device__ __forceinline__ unsigned pkh(float h, unsigned tag) {
  return (tag << 16) | (unsigned)__half_as_ushort(__float2half_rn(h));
}

// ---------------- GEMM: C[M][N] = A[M][K] @ B[N][K]^T + (b1+b2)[N] ----------------
// M=2048, N=8192, K=2048. 64x64 tile, K-tile 32, 256 threads, 4x4 outputs/thread.
// PACKED: A elements are u32 {tag16, f16} (LSTM h output); else plain f32.
template <bool PACKED>
__global__ __launch_bounds__(256, 2) void gemm_bias(
    const void* __restrict__ Av, const float* __restrict__ B,
    const float* __restrict__ b1, const float* __restrict__ b2,
    float* __restrict__ C)
{
  const int N = 8192, K = 2048;
  __shared__ float As[32][68];
  __shared__ float Bs[32][68];
  const int tid = threadIdx.x;
  const int tx = tid & 15, ty = tid >> 4;
  const int row0 = blockIdx.y * 64, col0 = blockIdx.x * 64;
  const int lk = (tid & 7) * 4, lr = tid >> 3;
  float acc[4][4] = {};
  for (int k0 = 0; k0 < K; k0 += 32) {
    float a0x, a0y, a0z, a0w, a1x, a1y, a1z, a1w;
    if (PACKED) {
      const unsigned* A = (const unsigned*)Av;
      uint4 u0 = *(const uint4*)&A[(size_t)(row0 + lr)      * K + k0 + lk];
      uint4 u1 = *(const uint4*)&A[(size_t)(row0 + lr + 32) * K + k0 + lk];
      a0x = uph(u0.x); a0y = uph(u0.y); a0z = uph(u0.z); a0w = uph(u0.w);
      a1x = uph(u1.x); a1y = uph(u1.y); a1z = uph(u1.z); a1w = uph(u1.w);
    } else {
      const float* A = (const float*)Av;
      float4 a0 = *(const float4*)&A[(size_t)(row0 + lr)      * K + k0 + lk];
      float4 a1 = *(const float4*)&A[(size_t)(row0 + lr + 32) * K + k0 + lk];
      a0x = a0.x; a0y = a0.y; a0z = a0.z; a0w = a0.w;
      a1x = a1.x; a1y = a1.y; a1z = a1.z; a1w = a1.w;
    }
    float4 bb0 = *(const float4*)&B[(size_t)(col0 + lr)      * K + k0 + lk];
    float4 bb1 = *(const float4*)&B[(size_t)(col0 + lr + 32) * K + k0 + lk];
    __syncthreads();
    As[lk+0][lr] = a0x;  As[lk+1][lr] = a0y;  As[lk+2][lr] = a0z;  As[lk+3][lr] = a0w;
    As[lk+0][lr+32] = a1x; As[lk+1][lr+32] = a1y; As[lk+2][lr+32] = a1z; As[lk+3][lr+32] = a1w;
    Bs[lk+0][lr] = bb0.x; Bs[lk+1][lr] = bb0.y; Bs[lk+2][lr] = bb0.z; Bs[lk+3][lr] = bb0.w;
    Bs[lk+0][lr+32] = bb1.x; Bs[lk+1][lr+32] = bb1.y; Bs[lk+2][lr+32] = bb1.z; Bs[lk+3][lr+32] = bb1.w;
    __syncthreads();
    #pragma unroll
    for (int kk = 0; kk < 32; ++kk) {
      float4 av = *(const float4*)&As[kk][ty * 4];
      float4 bv = *(const float4*)&Bs[kk][tx * 4];
      float am[4] = {av.x, av.y, av.z, av.w};
      float bm[4] = {bv.x, bv.y, bv.z, bv.w};
      #pragma unroll
      for (int i = 0; i < 4; ++i)
        #pragma unroll
        for (int j = 0; j < 4; ++j)
          acc[i][j] = fmaf(am[i], bm[j], acc[i][j]);
    }
  }
  #pragma unroll
  for (int i = 0; i < 4; ++i) {
    const int r = row0 + ty * 4 + i;
    #pragma unroll
    for (int j = 0; j < 4; ++j) {
      const int cc = col0 + tx * 4 + j;
      C[(size_t)r * N + cc] = acc[i][j] + b1[cc] + b2[cc];
    }
  }
}

// ---------------- Persistent recurrent kernel (one layer) ----------------
// 256 WGs x 512 threads, 1 WG/CU. WG b owns h indices [8b,8b+8); wave w computes
// all 4 gates of j = 8b+w. W_hh slice resident in VGPRs as packed f16.
//
// Handoff: each published h element is a u32 {tag=row (hi16), h=f16 (lo16)}
// stored with ONE relaxed agent-scope atomic — the data carries its own
// validity, so there is no flag array, no store drain, no release ordering,
// and only 2 coherence-point round trips on the critical path (store commit +
// poll detect). Polls spread over the 8KB row (256 lines) instead of a hot
// 1KB flag region. h_lds is double-buffered by step parity so the loop has a
// single __syncthreads (gather->dot); safety shown by barrier-separation.
__global__ __launch_bounds__(512, 2) void lstm_rec(
    const float* __restrict__ Whh,   // [8192][2048] this layer
    const float* __restrict__ G,     // [T][8192] x-contribution + biases
    const float* __restrict__ h0,    // [2048]
    const float* __restrict__ c0,    // [2048]
    unsigned* HbufP,                 // [T+1][2048] packed {tag,f16}; row r = h_{t=r-1}
    float* __restrict__ hn, float* __restrict__ cn)
{
  const int b = blockIdx.x;
  const int tid = threadIdx.x;
  const int w = tid >> 6;
  const int lane = tid & 63;
  const int j = b * 8 + w;
  __shared__ float h_lds[2][HID];

  // Weight fragment: lane holds elems {2*lane,2*lane+1}+128*it of rows g*2048+j.
  __half2 wreg[4][16];
  #pragma unroll
  for (int g = 0; g < 4; ++g) {
    const float* wrow = Whh + (size_t)(g * 2048 + j) * 2048 + 2 * lane;
    #pragma unroll
    for (int it = 0; it < 16; ++it) {
      float2 wv = *(const float2*)(wrow + 128 * it);
      wreg[g][it] = __floats2half2_rn(wv.x, wv.y);
    }
  }

  float cval = c0[j];       // broadcast same-address load, all lanes
  float hlast = 0.f;

  // Publish this WG's 8 elements of row 0 (= h0), tag 0. Fire-and-forget.
  if (tid < 8)
    __hip_atomic_store(&HbufP[b * 8 + tid], pkh(h0[b * 8 + tid], 0u),
                       __ATOMIC_RELAXED, __HIP_MEMORY_SCOPE_AGENT);

  const int i0 = tid, i1 = tid + 512, i2 = tid + 1024, i3 = tid + 1536;

  for (int r = 1; r <= T_LEN; ++r) {
    // Prefetch this step's G values (overlaps the gather wait).
    float gpre = (lane < 4) ? G[(size_t)(r - 1) * G4 + lane * 2048 + j] : 0.f;

    float* hbuf = h_lds[r & 1];
    const unsigned want = (unsigned)(r - 1);
    const unsigned* row = HbufP + (size_t)(r - 1) * HID;
    int sp = 0;
    for (;;) {
      unsigned va = __hip_atomic_load(&row[i0], __ATOMIC_RELAXED, __HIP_MEMORY_SCOPE_AGENT);
      unsigned vb = __hip_atomic_load(&row[i1], __ATOMIC_RELAXED, __HIP_MEMORY_SCOPE_AGENT);
      unsigned vc = __hip_atomic_load(&row[i2], __ATOMIC_RELAXED, __HIP_MEMORY_SCOPE_AGENT);
      unsigned vd = __hip_atomic_load(&row[i3], __ATOMIC_RELAXED, __HIP_MEMORY_SCOPE_AGENT);
      bool ok = ((va >> 16) == want) & ((vb >> 16) == want) &
                ((vc >> 16) == want) & ((vd >> 16) == want);
      if (ok) {
        hbuf[i0] = uph(va); hbuf[i1] = uph(vb);
        hbuf[i2] = uph(vc); hbuf[i3] = uph(vd);
        break;
      }
      if (++sp > 8) __builtin_amdgcn_s_sleep(1);   // light backoff vs fabric flood
      if (sp > (1 << 20)) break;                   // safety valve
    }
    __syncthreads();

    float a0 = 0.f, a1 = 0.f, a2 = 0.f, a3 = 0.f;
    #pragma unroll
    for (int it = 0; it < 16; ++it) {
      float2 hv = *(const float2*)&hbuf[2 * lane + 128 * it];
      float2 w0 = __half22float2(wreg[0][it]);
      float2 w1 = __half22float2(wreg[1][it]);
      float2 w2 = __half22float2(wreg[2][it]);
      float2 w3 = __half22float2(wreg[3][it]);
      a0 = fmaf(w0.x, hv.x, a0); a0 = fmaf(w0.y, hv.y, a0);
      a1 = fmaf(w1.x, hv.x, a1); a1 = fmaf(w1.y, hv.y, a1);
      a2 = fmaf(w2.x, hv.x, a2); a2 = fmaf(w2.y, hv.y, a2);
      a3 = fmaf(w3.x, hv.x, a3); a3 = fmaf(w3.y, hv.y, a3);
    }
    #pragma unroll
    for (int off = 32; off > 0; off >>= 1) {
      a0 += __shfl_xor(a0, off, 64);
      a1 += __shfl_xor(a1, off, 64);
      a2 += __shfl_xor(a2, off, 64);
      a3 += __shfl_xor(a3, off, 64);
    }
    float g0 = __shfl(gpre, 0, 64), g1 = __shfl(gpre, 1, 64);
    float g2 = __shfl(gpre, 2, 64), g3 = __shfl(gpre, 3, 64);
    // All lanes compute identically (no divergence, no broadcast needed).
    float pi = a0 + g0, pf = a1 + g1, pg = a2 + g2, po = a3 + g3;
    float ig = 1.f / (1.f + expf(-pi));
    float fg = 1.f / (1.f + expf(-pf));
    float gg = tanhf(pg);
    float og = 1.f / (1.f + expf(-po));
    cval = fg * cval + ig * gg;
    hlast = og * tanhf(cval);
    if (lane == 0)
      __hip_atomic_store(&HbufP[(size_t)r * HID + j], pkh(hlast, (unsigned)r),
                         __ATOMIC_RELAXED, __HIP_MEMORY_SCOPE_AGENT);
    // No end-of-step barrier: h_lds double buffer + the one barrier/step make
    // cross-parity reuse impossible (a wave can't get 2 barriers ahead).
  }
  if (lane == 0) { hn[j] = hlast; cn[j] = cval; }
}

// ---------------- FC + log_softmax ----------------
__global__ __launch_bounds__(128) void fc_lsm(
    const unsigned* __restrict__ Hrows,  // [T][2048] packed (HbufP1 + HID)
    const float* __restrict__ fcw,       // [128][2048]
    const float* __restrict__ fcb,       // [128]
    float* __restrict__ out)             // [T][128]
{
  const int t = blockIdx.x;
  const int v = threadIdx.x;
  __shared__ float hs[HID];
  __shared__ float red[4];
  const unsigned* hrow = Hrows + (size_t)t * HID;
  for (int q = v; q < HID / 4; q += 128) {
    uint4 uv = *(const uint4*)&hrow[q * 4];
    hs[q * 4 + 0] = uph(uv.x); hs[q * 4 + 1] = uph(uv.y);
    hs[q * 4 + 2] = uph(uv.z); hs[q * 4 + 3] = uph(uv.w);
  }
  __syncthreads();
  const float* wrow = fcw + (size_t)v * HID;
  float acc = fcb[v];
  #pragma unroll 4
  for (int k = 0; k < HID; k += 4) {
    float4 wv = *(const float4*)&wrow[k];
    acc = fmaf(wv.x, hs[k],     acc);
    acc = fmaf(wv.y, hs[k + 1], acc);
    acc = fmaf(wv.z, hs[k + 2], acc);
    acc = fmaf(wv.w, hs[k + 3], acc);
  }
  float m = acc;
  #pragma unroll
  for (int off = 32; off > 0; off >>= 1) m = fmaxf(m, __shfl_xor(m, off, 64));
  if ((v & 63) == 0) red[v >> 6] = m;
  __syncthreads();
  m = fmaxf(red[0], red[1]);
  float e = expf(acc - m), s = e;
  #pragma unroll
  for (int off = 32; off > 0; off >>= 1) s += __shfl_xor(s, off, 64);
  if ((v & 63) == 0) red[2 + (v >> 6)] = s;
  __syncthreads();
  s = red[2] + red[3];
  out[(size_t)t * NV + v] = (acc - m) - logf(s);
}

extern "C" void kernel_launch(void* const* d_in, const int* in_sizes, int n_in,
                              void* d_out, int out_size, void* d_ws, size_t ws_size,
                              hipStream_t stream) {
  const float* x   = (const float*)d_in[0];
  const float* h0  = (const float*)d_in[1];
  const float* c0  = (const float*)d_in[2];
  const float* Wih = (const float*)d_in[3];
  const float* Whh = (const float*)d_in[4];
  const float* bih = (const float*)d_in[5];
  const float* bhh = (const float*)d_in[6];
  const float* fcw = (const float*)d_in[7];
  const float* fcb = (const float*)d_in[8];
  float* out = (float*)d_out;

  // ws layout (bytes): G 67,108,864 | HbufP0 16,785,408 | HbufP1 16,785,408
  char* ws = (char*)d_ws;
  float*    G      = (float*)(ws);
  unsigned* HbufP0 = (unsigned*)(ws + 67108864);
  unsigned* HbufP1 = (unsigned*)(ws + 67108864 + 16785408);

  dim3 ggrid(G4 / 64, T_LEN / 64);  // (128, 32)

  // layer 0
  gemm_bias<false><<<ggrid, 256, 0, stream>>>(x, Wih, bih, bhh, G);
  lstm_rec<<<256, 512, 0, stream>>>(Whh, G, h0, c0, HbufP0,
                                    out + 262144, out + 266240);
  // layer 1 (input = layer-0 packed outputs, rows 1..T)
  gemm_bias<true><<<ggrid, 256, 0, stream>>>(HbufP0 + HID, Wih + (size_t)G4 * HID,
                                             bih + G4, bhh + G4, G);
  lstm_rec<<<256, 512, 0, stream>>>(Whh + (size_t)G4 * HID, G, h0 + HID, c0 + HID,
                                    HbufP1,
                                    out + 262144 + HID, out + 266240 + HID);
  // FC + log_softmax on layer-1 outputs
  fc_lsm<<<T_LEN, 128, 0, stream>>>(HbufP1 + HID, fcw, fcb, out);
}

// Round 5
// 21438.240 us; speedup vs baseline: 2.3472x; 1.1339x over previous
//
#include <hip/hip_runtime.h>
#include <hip/hip_fp16.h>

#define T_LEN 2048
#define HID   2048
#define G4    8192
#define NV    128

typedef _Float16 h2_t __attribute__((ext_vector_type(2)));

__device__ __forceinline__ float uph(unsigned u) {
  return __half2float(__ushort_as_half((unsigned short)(u & 0xffffu)));
}
__device__ __forceinline__ unsigned pkh(float h, unsigned tag) {
  return (tag << 16) | (unsigned)__half_as_ushort(__float2half_rn(h));
}
__device__ __forceinline__ h2_t pk2(float a, float bb) {
  return __builtin_bit_cast(h2_t, __builtin_amdgcn_cvt_pkrtz(a, bb));
}

// Coherent (L1/L2-bypassing) 16B load — 4 tagged elements per transaction.
__device__ __forceinline__ uint4 ld_sc16(const unsigned* p) {
  uint4 r;
  asm volatile("global_load_dwordx4 %0, %1, off sc0 sc1\n\ts_waitcnt vmcnt(0)"
               : "=v"(r) : "v"(p) : "memory");
  return r;
}

__device__ __forceinline__ float fsigmoid(float x) {
  return __builtin_amdgcn_rcpf(1.f + __expf(-x));
}
__device__ __forceinline__ float ftanh(float x) {
  return 2.f * __builtin_amdgcn_rcpf(1.f + __expf(-2.f * x)) - 1.f;
}

// ---------------- GEMM: C[M][N] = A[M][K] @ B[N][K]^T + (b1+b2)[N] ----------------
template <bool PACKED>
__global__ __launch_bounds__(256, 2) void gemm_bias(
    const void* __restrict__ Av, const float* __restrict__ B,
    const float* __restrict__ b1, const float* __restrict__ b2,
    float* __restrict__ C)
{
  const int N = 8192, K = 2048;
  __shared__ float As[32][68];
  __shared__ float Bs[32][68];
  const int tid = threadIdx.x;
  const int tx = tid & 15, ty = tid >> 4;
  const int row0 = blockIdx.y * 64, col0 = blockIdx.x * 64;
  const int lk = (tid & 7) * 4, lr = tid >> 3;
  float acc[4][4] = {};
  for (int k0 = 0; k0 < K; k0 += 32) {
    float a0x, a0y, a0z, a0w, a1x, a1y, a1z, a1w;
    if (PACKED) {
      const unsigned* A = (const unsigned*)Av;
      uint4 u0 = *(const uint4*)&A[(size_t)(row0 + lr)      * K + k0 + lk];
      uint4 u1 = *(const uint4*)&A[(size_t)(row0 + lr + 32) * K + k0 + lk];
      a0x = uph(u0.x); a0y = uph(u0.y); a0z = uph(u0.z); a0w = uph(u0.w);
      a1x = uph(u1.x); a1y = uph(u1.y); a1z = uph(u1.z); a1w = uph(u1.w);
    } else {
      const float* A = (const float*)Av;
      float4 a0 = *(const float4*)&A[(size_t)(row0 + lr)      * K + k0 + lk];
      float4 a1 = *(const float4*)&A[(size_t)(row0 + lr + 32) * K + k0 + lk];
      a0x = a0.x; a0y = a0.y; a0z = a0.z; a0w = a0.w;
      a1x = a1.x; a1y = a1.y; a1z = a1.z; a1w = a1.w;
    }
    float4 bb0 = *(const float4*)&B[(size_t)(col0 + lr)      * K + k0 + lk];
    float4 bb1 = *(const float4*)&B[(size_t)(col0 + lr + 32) * K + k0 + lk];
    __syncthreads();
    As[lk+0][lr] = a0x;  As[lk+1][lr] = a0y;  As[lk+2][lr] = a0z;  As[lk+3][lr] = a0w;
    As[lk+0][lr+32] = a1x; As[lk+1][lr+32] = a1y; As[lk+2][lr+32] = a1z; As[lk+3][lr+32] = a1w;
    Bs[lk+0][lr] = bb0.x; Bs[lk+1][lr] = bb0.y; Bs[lk+2][lr] = bb0.z; Bs[lk+3][lr] = bb0.w;
    Bs[lk+0][lr+32] = bb1.x; Bs[lk+1][lr+32] = bb1.y; Bs[lk+2][lr+32] = bb1.z; Bs[lk+3][lr+32] = bb1.w;
    __syncthreads();
    #pragma unroll
    for (int kk = 0; kk < 32; ++kk) {
      float4 av = *(const float4*)&As[kk][ty * 4];
      float4 bv = *(const float4*)&Bs[kk][tx * 4];
      float am[4] = {av.x, av.y, av.z, av.w};
      float bm[4] = {bv.x, bv.y, bv.z, bv.w};
      #pragma unroll
      for (int i = 0; i < 4; ++i)
        #pragma unroll
        for (int j = 0; j < 4; ++j)
          acc[i][j] = fmaf(am[i], bm[j], acc[i][j]);
    }
  }
  #pragma unroll
  for (int i = 0; i < 4; ++i) {
    const int r = row0 + ty * 4 + i;
    #pragma unroll
    for (int j = 0; j < 4; ++j) {
      const int cc = col0 + tx * 4 + j;
      C[(size_t)r * N + cc] = acc[i][j] + b1[cc] + b2[cc];
    }
  }
}

// ---------------- Persistent recurrent kernel (one layer) ----------------
// 256 WGs x 512 threads, 1 WG/CU. WG b owns h indices [8b,8b+8); wave w computes
// all 4 gates of j = 8b+w. W_hh slice resident in VGPRs as packed f16.
//
// Handoff: tagged data {tag=row(hi16), h=f16(lo16)} per element, relaxed
// agent-scope u32 stores (fire-and-forget, no drain/flags). Consumers poll
// with ONE 16B sc0/sc1 dwordx4 per thread (4 contiguous tagged elems) —
// 131K txns/round chip-wide vs R3's 524K scalar-atomic flood (the 10K-cycle
// queueing term). Dot uses v_dot2_f32_f16 on half2 pairs (~3x less VALU).
__global__ __launch_bounds__(512, 2) void lstm_rec(
    const float* __restrict__ Whh,   // [8192][2048] this layer
    const float* __restrict__ G,     // [T][8192] x-contribution + biases
    const float* __restrict__ h0,    // [2048]
    const float* __restrict__ c0,    // [2048]
    unsigned* HbufP,                 // [T+1][2048] packed; row r = h_{t=r-1}
    float* __restrict__ hn, float* __restrict__ cn)
{
  const int b = blockIdx.x;
  const int tid = threadIdx.x;
  const int w = tid >> 6;
  const int lane = tid & 63;
  const int j = b * 8 + w;
  // h as packed half2 pairs: hsu[p][i] holds {h[2i](lo16), h[2i+1](hi16)}
  __shared__ unsigned hsu[2][HID / 2];

  // Weight fragment: lane holds elems {2*lane,2*lane+1}+128*it of rows g*2048+j,
  // packed f32->f16 pairs (64 VGPRs).
  h2_t wreg[4][16];
  #pragma unroll
  for (int g = 0; g < 4; ++g) {
    const float* wrow = Whh + (size_t)(g * 2048 + j) * 2048 + 2 * lane;
    #pragma unroll
    for (int it = 0; it < 16; ++it) {
      float2 wv = *(const float2*)(wrow + 128 * it);
      wreg[g][it] = pk2(wv.x, wv.y);
    }
  }

  float cval = c0[j];       // broadcast same-address load, all lanes
  float hlast = 0.f;

  // Publish this WG's 8 elements of row 0 (= h0), tag 0.
  if (tid < 8)
    __hip_atomic_store(&HbufP[b * 8 + tid], pkh(h0[b * 8 + tid], 0u),
                       __ATOMIC_RELAXED, __HIP_MEMORY_SCOPE_AGENT);

  for (int r = 1; r <= T_LEN; ++r) {
    // Prefetch this step's G values (overlaps the gather wait).
    float gpre = (lane < 4) ? G[(size_t)(r - 1) * G4 + lane * 2048 + j] : 0.f;

    unsigned* hrow = hsu[r & 1];
    const unsigned want = (unsigned)(r - 1);
    const unsigned* src = HbufP + (size_t)(r - 1) * HID + 4 * tid;
    uint4 u;
    int sp = 0;
    for (;;) {
      u = ld_sc16(src);
      bool ok = ((u.x >> 16) == want) & ((u.y >> 16) == want) &
                ((u.z >> 16) == want) & ((u.w >> 16) == want);
      if (ok) break;
      if (++sp > 4) __builtin_amdgcn_s_sleep(1);   // backoff vs fabric flood
      if (sp > (1 << 20)) break;                   // safety valve
    }
    // Strip tags, pack h pairs, one 8B LDS store.
    unsigned p01 = (u.x & 0xffffu) | (u.y << 16);
    unsigned p23 = (u.z & 0xffffu) | (u.w << 16);
    *(uint2*)&hrow[2 * tid] = make_uint2(p01, p23);
    __syncthreads();

    float a0 = 0.f, a1 = 0.f, a2 = 0.f, a3 = 0.f;
    #pragma unroll
    for (int it = 0; it < 16; ++it) {
      h2_t hv = __builtin_bit_cast(h2_t, hrow[lane + 64 * it]);
      a0 = __builtin_amdgcn_fdot2(wreg[0][it], hv, a0, false);
      a1 = __builtin_amdgcn_fdot2(wreg[1][it], hv, a1, false);
      a2 = __builtin_amdgcn_fdot2(wreg[2][it], hv, a2, false);
      a3 = __builtin_amdgcn_fdot2(wreg[3][it], hv, a3, false);
    }
    #pragma unroll
    for (int off = 32; off > 0; off >>= 1) {
      a0 += __shfl_xor(a0, off, 64);
      a1 += __shfl_xor(a1, off, 64);
      a2 += __shfl_xor(a2, off, 64);
      a3 += __shfl_xor(a3, off, 64);
    }
    float g0 = __shfl(gpre, 0, 64), g1 = __shfl(gpre, 1, 64);
    float g2 = __shfl(gpre, 2, 64), g3 = __shfl(gpre, 3, 64);
    // All lanes compute identically (no divergence).
    float ig = fsigmoid(a0 + g0);
    float fg = fsigmoid(a1 + g1);
    float gg = ftanh(a2 + g2);
    float og = fsigmoid(a3 + g3);
    cval = fg * cval + ig * gg;
    hlast = og * ftanh(cval);
    if (lane == 0)
      __hip_atomic_store(&HbufP[(size_t)r * HID + j], pkh(hlast, (unsigned)r),
                         __ATOMIC_RELAXED, __HIP_MEMORY_SCOPE_AGENT);
    // No end-of-step barrier: double-buffered hsu + one barrier/step means no
    // wave can touch the other parity's buffer while it's still being read.
  }
  if (lane == 0) { hn[j] = hlast; cn[j] = cval; }
}

// ---------------- FC + log_softmax ----------------
__global__ __launch_bounds__(128) void fc_lsm(
    const unsigned* __restrict__ Hrows,  // [T][2048] packed (HbufP1 + HID)
    const float* __restrict__ fcw,       // [128][2048]
    const float* __restrict__ fcb,       // [128]
    float* __restrict__ out)             // [T][128]
{
  const int t = blockIdx.x;
  const int v = threadIdx.x;
  __shared__ float hs[HID];
  __shared__ float red[4];
  const unsigned* hrow = Hrows + (size_t)t * HID;
  for (int q = v; q < HID / 4; q += 128) {
    uint4 uv = *(const uint4*)&hrow[q * 4];
    hs[q * 4 + 0] = uph(uv.x); hs[q * 4 + 1] = uph(uv.y);
    hs[q * 4 + 2] = uph(uv.z); hs[q * 4 + 3] = uph(uv.w);
  }
  __syncthreads();
  const float* wrow = fcw + (size_t)v * HID;
  float acc = fcb[v];
  #pragma unroll 4
  for (int k = 0; k < HID; k += 4) {
    float4 wv = *(const float4*)&wrow[k];
    acc = fmaf(wv.x, hs[k],     acc);
    acc = fmaf(wv.y, hs[k + 1], acc);
    acc = fmaf(wv.z, hs[k + 2], acc);
    acc = fmaf(wv.w, hs[k + 3], acc);
  }
  float m = acc;
  #pragma unroll
  for (int off = 32; off > 0; off >>= 1) m = fmaxf(m, __shfl_xor(m, off, 64));
  if ((v & 63) == 0) red[v >> 6] = m;
  __syncthreads();
  m = fmaxf(red[0], red[1]);
  float e = expf(acc - m), s = e;
  #pragma unroll
  for (int off = 32; off > 0; off >>= 1) s += __shfl_xor(s, off, 64);
  if ((v & 63) == 0) red[2 + (v >> 6)] = s;
  __syncthreads();
  s = red[2] + red[3];
  out[(size_t)t * NV + v] = (acc - m) - logf(s);
}

extern "C" void kernel_launch(void* const* d_in, const int* in_sizes, int n_in,
                              void* d_out, int out_size, void* d_ws, size_t ws_size,
                              hipStream_t stream) {
  const float* x   = (const float*)d_in[0];
  const float* h0  = (const float*)d_in[1];
  const float* c0  = (const float*)d_in[2];
  const float* Wih = (const float*)d_in[3];
  const float* Whh = (const float*)d_in[4];
  const float* bih = (const float*)d_in[5];
  const float* bhh = (const float*)d_in[6];
  const float* fcw = (const float*)d_in[7];
  const float* fcb = (const float*)d_in[8];
  float* out = (float*)d_out;

  // ws layout (bytes): G 67,108,864 | HbufP0 16,785,408 | HbufP1 16,785,408
  char* ws = (char*)d_ws;
  float*    G      = (float*)(ws);
  unsigned* HbufP0 = (unsigned*)(ws + 67108864);
  unsigned* HbufP1 = (unsigned*)(ws + 67108864 + 16785408);

  dim3 ggrid(G4 / 64, T_LEN / 64);  // (128, 32)

  // layer 0
  gemm_bias<false><<<ggrid, 256, 0, stream>>>(x, Wih, bih, bhh, G);
  lstm_rec<<<256, 512, 0, stream>>>(Whh, G, h0, c0, HbufP0,
                                    out + 262144, out + 266240);
  // layer 1 (input = layer-0 packed outputs, rows 1..T)
  gemm_bias<true><<<ggrid, 256, 0, stream>>>(HbufP0 + HID, Wih + (size_t)G4 * HID,
                                             bih + G4, bhh + G4, G);
  lstm_rec<<<256, 512, 0, stream>>>(Whh + (size_t)G4 * HID, G, h0 + HID, c0 + HID,
                                    HbufP1,
                                    out + 262144 + HID, out + 266240 + HID);
  // FC + log_softmax on layer-1 outputs
  fc_lsm<<<T_LEN, 128, 0, stream>>>(HbufP1 + HID, fcw, fcb, out);
}